// Round 1
// baseline (384.487 us; speedup 1.0000x reference)
//
#include <hip/hip_runtime.h>

typedef __bf16 bf16_t;
typedef __bf16 bf16x8 __attribute__((ext_vector_type(8)));
typedef float f32x4 __attribute__((ext_vector_type(4)));

#define GM 16384   // rows of x / out
#define GN 2048    // D_OUT
#define GK 2048    // D_IN
#define NX (GM * GK)
#define NW (GN * GK)

#define BM 256
#define BN 256
#define BK 64
#define NT (GK / BK)   // 32 K-tiles

// -------- merged fp32 -> bf16 convert (8 elems/thread, nt loads) --------
__global__ __launch_bounds__(256) void cvt_all(const float* __restrict__ x,
                                               const float* __restrict__ w,
                                               bf16_t* __restrict__ xb,
                                               bf16_t* __restrict__ wb) {
    long i = ((long)blockIdx.x * 256 + threadIdx.x) * 8;
    const float* s;
    bf16_t* d;
    if (i < NX) { s = x + i; d = xb + i; }          // wave-uniform branch
    else        { s = w + (i - NX); d = wb + (i - NX); }
    f32x4 v0 = __builtin_nontemporal_load((const f32x4*)s);
    f32x4 v1 = __builtin_nontemporal_load((const f32x4*)(s + 4));
    bf16x8 o;
    o[0] = (bf16_t)v0.x; o[1] = (bf16_t)v0.y; o[2] = (bf16_t)v0.z; o[3] = (bf16_t)v0.w;
    o[4] = (bf16_t)v1.x; o[5] = (bf16_t)v1.y; o[6] = (bf16_t)v1.z; o[7] = (bf16_t)v1.w;
    *(bf16x8*)d = o;   // bf16 stays cacheable — GEMM re-reads it
}

// -------- async global->LDS, 16B per lane --------
__device__ __forceinline__ void async16(const void* g, void* l) {
    __builtin_amdgcn_global_load_lds(
        (__attribute__((address_space(1))) void*)g,
        (__attribute__((address_space(3))) void*)l,
        16, 0, 0);
}

#define MEMBAR() asm volatile("" ::: "memory")

// -------- GEMM: C = A * B^T * scale + 0.1*bias --------
// 256x256 tile, BK=64, 8 waves (2M x 4N), 128x64 output per wave.
// Double-buffered XOR-swizzled LDS (128 KiB). Phase-split K-tile:
// 4 phases x {ds_read frags -> s_barrier -> setprio(1) 16 MFMA setprio(0)
// -> s_barrier}. Next K-tile's 8 global_load_lds are issued at iteration
// top and stay IN FLIGHT across all phase barriers (raw s_barrier, no
// vmcnt drain); the only vmcnt(0) is at the iteration boundary where the
// loads are a full iteration old.
// Swizzle (proven, 0 bank conflicts): 16B chunk (row, g) of a tile lives
// at position (row, g ^ (row&7)); staging permutes the GLOBAL fetch per
// lane, keeping the LDS destination linear as global_load_lds requires.
__global__ __launch_bounds__(512, 2) void gemm_bf16_bt(
    const bf16_t* __restrict__ A,
    const bf16_t* __restrict__ B,
    const float* __restrict__ bias,
    float* __restrict__ C) {
    __shared__ bf16_t As[2][BM * BK];   // 2 x 32 KB
    __shared__ bf16_t Bs[2][BN * BK];   // 2 x 32 KB

    const int t = threadIdx.x;

    // XCD-aware chunked swizzle: 512 wgs, 64 contiguous tiles per XCD.
    const int orig = blockIdx.y * 8 + blockIdx.x;      // gridDim.x == 8
    const int swz  = (orig & 7) * 64 + (orig >> 3);    // bijective (512%8==0)
    const int bn0  = (swz & 7) * BN;
    const int bm0  = (swz >> 3) * BM;

    const int wave = t >> 6;
    const int lane = t & 63;
    const int wm   = wave >> 2;        // 0..1 (M half)
    const int wn   = wave & 3;         // 0..3 (N quarter)
    const int fr   = lane & 15;        // frag row == C col
    const int quad = lane >> 4;
    const int sz   = fr & 7;
    const int ch0  = (quad ^ sz) * 8;        // k-half 0 chunk offset (elems)
    const int ch1  = ((4 + quad) ^ sz) * 8;  // k-half 1

    // Staging: issue round i covers tile rows [i*64, i*64+64).
    // Thread t -> LDS chunk (i*512 + t): row = i*64 + (t>>3), stored g = t&7,
    // fetches global col-group (t&7) ^ (row&7).
    const int srow = t >> 3;                          // 0..63
    const int scol = (((t & 7) ^ (srow & 7)) * 8);
    const bf16_t* gA = A + (size_t)(bm0 + srow) * GK + scol;
    const bf16_t* gB = B + (size_t)(bn0 + srow) * GK + scol;

    f32x4 acc[8][4] = {};

    // ---- prologue: stage K-tile 0 into buffer 0 ----
#pragma unroll
    for (int i = 0; i < 4; ++i)
        async16(gA + (size_t)(i * 64) * GK, &As[0][(i * 512 + t) * 8]);
#pragma unroll
    for (int i = 0; i < 4; ++i)
        async16(gB + (size_t)(i * 64) * GK, &Bs[0][(i * 512 + t) * 8]);
    asm volatile("s_waitcnt vmcnt(0)" ::: "memory");
    __builtin_amdgcn_s_barrier();

    const int abase = (wm * 128 + fr) * BK;   // + mq*64*BK + fi*16*BK
    const int bbase = (wn * 64 + fr) * BK;

    for (int kt = 0; kt < NT; ++kt) {
        const int cur = kt & 1;
        const bf16_t* Ac = As[cur];
        const bf16_t* Bc = Bs[cur];

        // Prefetch next K-tile into the other buffer; these 8 loads stay
        // in flight across the phase barriers below.
        if (kt + 1 < NT) {
            const size_t koff = (size_t)(kt + 1) * BK;
            bf16_t* Ad = As[cur ^ 1];
            bf16_t* Bd = Bs[cur ^ 1];
#pragma unroll
            for (int i = 0; i < 4; ++i)
                async16(gA + (size_t)(i * 64) * GK + koff, &Ad[(i * 512 + t) * 8]);
#pragma unroll
            for (int i = 0; i < 4; ++i)
                async16(gB + (size_t)(i * 64) * GK + koff, &Bd[(i * 512 + t) * 8]);
        }

        bf16x8 af[4], bf[4];

        // ---- phase 0: k-half 0, m-quadrant 0 ----
#pragma unroll
        for (int i = 0; i < 4; ++i)
            bf[i] = *(const bf16x8*)&Bc[bbase + i * 16 * BK + ch0];
#pragma unroll
        for (int i = 0; i < 4; ++i)
            af[i] = *(const bf16x8*)&Ac[abase + i * 16 * BK + ch0];
        MEMBAR();
        __builtin_amdgcn_s_barrier();
        __builtin_amdgcn_s_setprio(1);
#pragma unroll
        for (int mi = 0; mi < 4; ++mi)
#pragma unroll
            for (int ni = 0; ni < 4; ++ni)
                acc[mi][ni] = __builtin_amdgcn_mfma_f32_16x16x32_bf16(
                    af[mi], bf[ni], acc[mi][ni], 0, 0, 0);
        __builtin_amdgcn_s_setprio(0);
        MEMBAR();
        __builtin_amdgcn_s_barrier();

        // ---- phase 1: k-half 0, m-quadrant 1 ----
#pragma unroll
        for (int i = 0; i < 4; ++i)
            af[i] = *(const bf16x8*)&Ac[abase + 64 * BK + i * 16 * BK + ch0];
        MEMBAR();
        __builtin_amdgcn_s_barrier();
        __builtin_amdgcn_s_setprio(1);
#pragma unroll
        for (int mi = 0; mi < 4; ++mi)
#pragma unroll
            for (int ni = 0; ni < 4; ++ni)
                acc[4 + mi][ni] = __builtin_amdgcn_mfma_f32_16x16x32_bf16(
                    af[mi], bf[ni], acc[4 + mi][ni], 0, 0, 0);
        __builtin_amdgcn_s_setprio(0);
        MEMBAR();
        __builtin_amdgcn_s_barrier();

        // ---- phase 2: k-half 1, m-quadrant 0 ----
#pragma unroll
        for (int i = 0; i < 4; ++i)
            bf[i] = *(const bf16x8*)&Bc[bbase + i * 16 * BK + ch1];
#pragma unroll
        for (int i = 0; i < 4; ++i)
            af[i] = *(const bf16x8*)&Ac[abase + i * 16 * BK + ch1];
        MEMBAR();
        __builtin_amdgcn_s_barrier();
        __builtin_amdgcn_s_setprio(1);
#pragma unroll
        for (int mi = 0; mi < 4; ++mi)
#pragma unroll
            for (int ni = 0; ni < 4; ++ni)
                acc[mi][ni] = __builtin_amdgcn_mfma_f32_16x16x32_bf16(
                    af[mi], bf[ni], acc[mi][ni], 0, 0, 0);
        __builtin_amdgcn_s_setprio(0);
        MEMBAR();
        __builtin_amdgcn_s_barrier();

        // ---- phase 3: k-half 1, m-quadrant 1 (no trailing phase barrier) ----
#pragma unroll
        for (int i = 0; i < 4; ++i)
            af[i] = *(const bf16x8*)&Ac[abase + 64 * BK + i * 16 * BK + ch1];
        MEMBAR();
        __builtin_amdgcn_s_barrier();
        __builtin_amdgcn_s_setprio(1);
#pragma unroll
        for (int mi = 0; mi < 4; ++mi)
#pragma unroll
            for (int ni = 0; ni < 4; ++ni)
                acc[4 + mi][ni] = __builtin_amdgcn_mfma_f32_16x16x32_bf16(
                    af[mi], bf[ni], acc[4 + mi][ni], 0, 0, 0);
        __builtin_amdgcn_s_setprio(0);

        // Iteration boundary: next K-tile's loads (issued ~1 full iteration
        // ago) must have landed; all waves' reads of buf[cur] are already
        // architecturally drained (consumed by MFMAs above).
        asm volatile("s_waitcnt vmcnt(0)" ::: "memory");
        __builtin_amdgcn_s_barrier();
    }

    // Epilogue: C/D layout col=lane&15, row=quad*4+reg [m89-verified].
    const float scale = 0.022097086912079608f;  // 1/sqrt(2048)
    const int crow0 = bm0 + wm * 128 + (quad << 2);
    const int ccol0 = bn0 + wn * 64 + fr;
#pragma unroll
    for (int ni = 0; ni < 4; ++ni) {
        const int col = ccol0 + ni * 16;
        const float bv = 0.1f * bias[col];
#pragma unroll
        for (int mi = 0; mi < 8; ++mi) {
            const int row = crow0 + (mi >> 2) * 64 + (mi & 3) * 16;
#pragma unroll
            for (int r = 0; r < 4; ++r)
                __builtin_nontemporal_store(acc[mi][ni][r] * scale + bv,
                                            &C[(size_t)(row + r) * GN + col]);
        }
    }
}

extern "C" void kernel_launch(void* const* d_in, const int* in_sizes, int n_in,
                              void* d_out, int out_size, void* d_ws, size_t ws_size,
                              hipStream_t stream) {
    const float* x = (const float*)d_in[0];   // [16384, 2048]
    const float* w = (const float*)d_in[1];   // [2048, 2048]
    const float* b = (const float*)d_in[2];   // [1, 2048]
    float* out = (float*)d_out;               // [16384, 2048]

    bf16_t* xb = (bf16_t*)d_ws;                   // 64 MiB
    bf16_t* wb = xb + (size_t)NX;                 // + 8 MiB

    cvt_all<<<(NX + NW) / (8 * 256), 256, 0, stream>>>(x, w, xb, wb);

    dim3 grid(GN / BN, GM / BM);   // (8, 64) = 512 blocks
    gemm_bf16_bt<<<grid, 512, 0, stream>>>(xb, wb, b, out);
}

// Round 2
// 370.580 us; speedup vs baseline: 1.0375x; 1.0375x over previous
//
#include <hip/hip_runtime.h>

typedef __bf16 bf16_t;
typedef __bf16 bf16x8 __attribute__((ext_vector_type(8)));
typedef float f32x4 __attribute__((ext_vector_type(4)));

#define GM 16384   // rows of x / out
#define GN 2048    // D_OUT
#define GK 2048    // D_IN
#define NX (GM * GK)
#define NW (GN * GK)

#define BM 256
#define BN 256
#define BK 64
#define NT (GK / BK)   // 32 K-tiles

// -------- merged fp32 -> bf16 convert (8 elems/thread, nt loads) --------
__global__ __launch_bounds__(256) void cvt_all(const float* __restrict__ x,
                                               const float* __restrict__ w,
                                               bf16_t* __restrict__ xb,
                                               bf16_t* __restrict__ wb) {
    long i = ((long)blockIdx.x * 256 + threadIdx.x) * 8;
    const float* s;
    bf16_t* d;
    if (i < NX) { s = x + i; d = xb + i; }          // wave-uniform branch
    else        { s = w + (i - NX); d = wb + (i - NX); }
    f32x4 v0 = __builtin_nontemporal_load((const f32x4*)s);
    f32x4 v1 = __builtin_nontemporal_load((const f32x4*)(s + 4));
    bf16x8 o;
    o[0] = (bf16_t)v0.x; o[1] = (bf16_t)v0.y; o[2] = (bf16_t)v0.z; o[3] = (bf16_t)v0.w;
    o[4] = (bf16_t)v1.x; o[5] = (bf16_t)v1.y; o[6] = (bf16_t)v1.z; o[7] = (bf16_t)v1.w;
    *(bf16x8*)d = o;   // bf16 stays cacheable — GEMM re-reads it
}

// -------- async global->LDS, 16B per lane --------
__device__ __forceinline__ void async16(const void* g, void* l) {
    __builtin_amdgcn_global_load_lds(
        (__attribute__((address_space(1))) void*)g,
        (__attribute__((address_space(3))) void*)l,
        16, 0, 0);
}

#define MEMBAR() asm volatile("" ::: "memory")
#define BARRIER() do { MEMBAR(); __builtin_amdgcn_s_barrier(); MEMBAR(); } while (0)

// -------- GEMM: C = A * B^T * scale + 0.1*bias --------
// 256x256 tile, BK=64, 8 waves (2M x 4N), 128x64 output per wave.
// Double-buffered XOR-swizzled LDS (128 KiB), 1 block/CU.
// Schedule: ONE unfenced compute region per K-tile (24 ds_read_b128 +
// 64 MFMA — compiler interleaves LDS under MFMA, like the 128^2 kernel
// that measured 45% MfmaUtil), two barriers per K-tile, and a COUNTED
// vmcnt(8): tile kt+2's 8 global_load_lds are issued before the wait,
// so the wait drains only the batch issued one full K-tile earlier and
// 8 loads always stay in flight (never vmcnt(0) in steady state).
// Swizzle (proven, 0 bank conflicts): 16B chunk (row, g) of a tile lives
// at position (row, g ^ (row&7)); staging permutes the GLOBAL fetch per
// lane, keeping the LDS destination linear as global_load_lds requires.
__global__ __launch_bounds__(512, 2) void gemm_bf16_bt(
    const bf16_t* __restrict__ A,
    const bf16_t* __restrict__ B,
    const float* __restrict__ bias,
    float* __restrict__ C) {
    __shared__ bf16_t As[2][BM * BK];   // 2 x 32 KB
    __shared__ bf16_t Bs[2][BN * BK];   // 2 x 32 KB

    const int t = threadIdx.x;

    // XCD-aware chunked swizzle: 512 wgs, 64 contiguous tiles per XCD.
    const int orig = blockIdx.y * 8 + blockIdx.x;      // gridDim.x == 8
    const int swz  = (orig & 7) * 64 + (orig >> 3);    // bijective (512%8==0)
    const int bn0  = (swz & 7) * BN;
    const int bm0  = (swz >> 3) * BM;

    const int wave = t >> 6;
    const int lane = t & 63;
    const int wm   = wave >> 2;        // 0..1 (M half)
    const int wn   = wave & 3;         // 0..3 (N quarter)
    const int fr   = lane & 15;        // frag row == C col
    const int quad = lane >> 4;
    const int sz   = fr & 7;
    const int ch0  = (quad ^ sz) * 8;        // k-half 0 chunk offset (elems)
    const int ch1  = ((4 + quad) ^ sz) * 8;  // k-half 1

    // Staging: issue round i covers tile rows [i*64, i*64+64).
    // Thread t -> LDS chunk (i*512 + t): row = i*64 + (t>>3), stored g = t&7,
    // fetches global col-group (t&7) ^ (row&7).
    const int srow = t >> 3;                          // 0..63
    const int scol = (((t & 7) ^ (srow & 7)) * 8);
    const bf16_t* gA = A + (size_t)(bm0 + srow) * GK + scol;
    const bf16_t* gB = B + (size_t)(bn0 + srow) * GK + scol;

    f32x4 acc[8][4] = {};

    // ---- prologue: stage K-tiles 0 and 1; wait only tile 0 ----
#pragma unroll
    for (int i = 0; i < 4; ++i) {
        async16(gA + (size_t)(i * 64) * GK, &As[0][(i * 512 + t) * 8]);
        async16(gB + (size_t)(i * 64) * GK, &Bs[0][(i * 512 + t) * 8]);
    }
#pragma unroll
    for (int i = 0; i < 4; ++i) {
        async16(gA + (size_t)(i * 64) * GK + BK, &As[1][(i * 512 + t) * 8]);
        async16(gB + (size_t)(i * 64) * GK + BK, &Bs[1][(i * 512 + t) * 8]);
    }
    asm volatile("s_waitcnt vmcnt(8)" ::: "memory");   // tile 0 landed
    BARRIER();

    const int abase = (wm * 128 + fr) * BK;
    const int bbase = (wn * 64 + fr) * BK;

    for (int kt = 0; kt < NT; ++kt) {
        const int cur = kt & 1;
        const bf16_t* Ac = As[cur];
        const bf16_t* Bc = Bs[cur];

        // ---- one unfenced compute region: 24 ds_read_b128 + 64 MFMA ----
        bf16x8 af[4], bf[4];

        // k-half 0, m-quadrant 0
#pragma unroll
        for (int i = 0; i < 4; ++i)
            bf[i] = *(const bf16x8*)&Bc[bbase + i * 16 * BK + ch0];
#pragma unroll
        for (int i = 0; i < 4; ++i)
            af[i] = *(const bf16x8*)&Ac[abase + i * 16 * BK + ch0];
#pragma unroll
        for (int mi = 0; mi < 4; ++mi)
#pragma unroll
            for (int ni = 0; ni < 4; ++ni)
                acc[mi][ni] = __builtin_amdgcn_mfma_f32_16x16x32_bf16(
                    af[mi], bf[ni], acc[mi][ni], 0, 0, 0);

        // k-half 0, m-quadrant 1
#pragma unroll
        for (int i = 0; i < 4; ++i)
            af[i] = *(const bf16x8*)&Ac[abase + 64 * BK + i * 16 * BK + ch0];
#pragma unroll
        for (int mi = 0; mi < 4; ++mi)
#pragma unroll
            for (int ni = 0; ni < 4; ++ni)
                acc[4 + mi][ni] = __builtin_amdgcn_mfma_f32_16x16x32_bf16(
                    af[mi], bf[ni], acc[4 + mi][ni], 0, 0, 0);

        // k-half 1, m-quadrant 0
#pragma unroll
        for (int i = 0; i < 4; ++i)
            bf[i] = *(const bf16x8*)&Bc[bbase + i * 16 * BK + ch1];
#pragma unroll
        for (int i = 0; i < 4; ++i)
            af[i] = *(const bf16x8*)&Ac[abase + i * 16 * BK + ch1];
#pragma unroll
        for (int mi = 0; mi < 4; ++mi)
#pragma unroll
            for (int ni = 0; ni < 4; ++ni)
                acc[mi][ni] = __builtin_amdgcn_mfma_f32_16x16x32_bf16(
                    af[mi], bf[ni], acc[mi][ni], 0, 0, 0);

        // k-half 1, m-quadrant 1
#pragma unroll
        for (int i = 0; i < 4; ++i)
            af[i] = *(const bf16x8*)&Ac[abase + 64 * BK + i * 16 * BK + ch1];
#pragma unroll
        for (int mi = 0; mi < 4; ++mi)
#pragma unroll
            for (int ni = 0; ni < 4; ++ni)
                acc[4 + mi][ni] = __builtin_amdgcn_mfma_f32_16x16x32_bf16(
                    af[mi], bf[ni], acc[4 + mi][ni], 0, 0, 0);

        if (kt == NT - 1) break;

        BARRIER();   // all waves done reading buf cur

        // Refill buf cur with tile kt+2; counted wait drains only the
        // kt+1 batch (issued one full K-tile of compute ago).
        if (kt + 2 < NT) {
            const size_t koff = (size_t)(kt + 2) * BK;
            bf16_t* Ad = As[cur];
            bf16_t* Bd = Bs[cur];
#pragma unroll
            for (int i = 0; i < 4; ++i) {
                async16(gA + (size_t)(i * 64) * GK + koff, &Ad[(i * 512 + t) * 8]);
                async16(gB + (size_t)(i * 64) * GK + koff, &Bd[(i * 512 + t) * 8]);
            }
            asm volatile("s_waitcnt vmcnt(8)" ::: "memory");
        } else {
            asm volatile("s_waitcnt vmcnt(0)" ::: "memory");
        }

        BARRIER();   // buf cur^1 visible to all waves
    }

    // Epilogue: C/D layout col=lane&15, row=quad*4+reg [m89-verified].
    const float scale = 0.022097086912079608f;  // 1/sqrt(2048)
    const int crow0 = bm0 + wm * 128 + (quad << 2);
    const int ccol0 = bn0 + wn * 64 + fr;
#pragma unroll
    for (int ni = 0; ni < 4; ++ni) {
        const int col = ccol0 + ni * 16;
        const float bv = 0.1f * bias[col];
#pragma unroll
        for (int mi = 0; mi < 8; ++mi) {
            const int row = crow0 + (mi >> 2) * 64 + (mi & 3) * 16;
#pragma unroll
            for (int r = 0; r < 4; ++r)
                __builtin_nontemporal_store(acc[mi][ni][r] * scale + bv,
                                            &C[(size_t)(row + r) * GN + col]);
        }
    }
}

extern "C" void kernel_launch(void* const* d_in, const int* in_sizes, int n_in,
                              void* d_out, int out_size, void* d_ws, size_t ws_size,
                              hipStream_t stream) {
    const float* x = (const float*)d_in[0];   // [16384, 2048]
    const float* w = (const float*)d_in[1];   // [2048, 2048]
    const float* b = (const float*)d_in[2];   // [1, 2048]
    float* out = (float*)d_out;               // [16384, 2048]

    bf16_t* xb = (bf16_t*)d_ws;                   // 64 MiB
    bf16_t* wb = xb + (size_t)NX;                 // + 8 MiB

    cvt_all<<<(NX + NW) / (8 * 256), 256, 0, stream>>>(x, w, xb, wb);

    dim3 grid(GN / BN, GM / BM);   // (8, 64) = 512 blocks
    gemm_bf16_bt<<<grid, 512, 0, stream>>>(xb, wb, b, out);
}

// Round 3
// 351.375 us; speedup vs baseline: 1.0942x; 1.0547x over previous
//
#include <hip/hip_runtime.h>

typedef __bf16 bf16_t;
typedef __bf16 bf16x8 __attribute__((ext_vector_type(8)));
typedef float f32x4 __attribute__((ext_vector_type(4)));

#define GM 16384   // rows of x / out
#define GN 2048    // D_OUT
#define GK 2048    // D_IN
#define NX (GM * GK)
#define NW (GN * GK)

#define BM 256
#define BN 256
#define BK 64
#define NT (GK / BK)   // 32 K-tiles

// -------- merged fp32 -> bf16 convert (8 elems/thread, nt loads) --------
__global__ __launch_bounds__(256) void cvt_all(const float* __restrict__ x,
                                               const float* __restrict__ w,
                                               bf16_t* __restrict__ xb,
                                               bf16_t* __restrict__ wb) {
    long i = ((long)blockIdx.x * 256 + threadIdx.x) * 8;
    const float* s;
    bf16_t* d;
    if (i < NX) { s = x + i; d = xb + i; }          // wave-uniform branch
    else        { s = w + (i - NX); d = wb + (i - NX); }
    f32x4 v0 = __builtin_nontemporal_load((const f32x4*)s);
    f32x4 v1 = __builtin_nontemporal_load((const f32x4*)(s + 4));
    bf16x8 o;
    o[0] = (bf16_t)v0.x; o[1] = (bf16_t)v0.y; o[2] = (bf16_t)v0.z; o[3] = (bf16_t)v0.w;
    o[4] = (bf16_t)v1.x; o[5] = (bf16_t)v1.y; o[6] = (bf16_t)v1.z; o[7] = (bf16_t)v1.w;
    *(bf16x8*)d = o;   // bf16 stays cacheable — GEMM re-reads it
}

// -------- async global->LDS, 16B per lane --------
__device__ __forceinline__ void async16(const void* g, void* l) {
    __builtin_amdgcn_global_load_lds(
        (__attribute__((address_space(1))) void*)g,
        (__attribute__((address_space(3))) void*)l,
        16, 0, 0);
}

#define MEMBAR() asm volatile("" ::: "memory")

// -------- GEMM: C = A * B^T * scale + 0.1*bias --------
// 256x256 tile, BK=64, 8 waves, m201-style 4-phase/K-tile schedule.
// Phase = one 128x128 C-quadrant (mh,nh) x K=64; all 8 waves jointly
// compute it (wave sub-tile 64x32 -> 16 MFMA). Per phase: small ds_read
// burst (12/4/8/0 b128) + ONE half-tile stage (2 global_load_lds) +
// double barrier around the MFMA cluster (T3) + setprio (T5).
// Staging lifetimes (LDS half-region last read): A0@P1, B0@P1, B1@P2,
// A1@P3 -> stage B1,A1 of tile t+1 in P1,P2 (other buffer) and A0,B0 of
// tile t+2 in P3,P4 (CURRENT buffer, regions dead after P1). Boundary
// wait is a counted vmcnt(4) (T4): proves all halves the next tile needs,
// keeps 2 half-tiles permanently in flight. Never vmcnt(0) until the tail.
// Swizzle (proven, 0 conflicts): chunk (row,g) stored at g ^ (row&7);
// staging pre-swizzles the GLOBAL fetch, LDS dest stays linear.
__global__ __launch_bounds__(512, 2) void gemm_bf16_bt(
    const bf16_t* __restrict__ A,
    const bf16_t* __restrict__ B,
    const float* __restrict__ bias,
    float* __restrict__ C) {
    __shared__ bf16_t As[2][BM * BK];   // 2 x 32 KB
    __shared__ bf16_t Bs[2][BN * BK];   // 2 x 32 KB

    const int t = threadIdx.x;

    // XCD-aware chunked swizzle: 512 wgs, 64 contiguous tiles per XCD.
    const int orig = blockIdx.y * 8 + blockIdx.x;      // gridDim.x == 8
    const int swz  = (orig & 7) * 64 + (orig >> 3);    // bijective (512%8==0)
    const int bn0  = (swz & 7) * BN;
    const int bm0  = (swz >> 3) * BM;

    const int lane = t & 63;
    const int wave = t >> 6;
    const int wr   = wave >> 2;        // 0..1: 64-row block within quadrant
    const int wc   = wave & 3;         // 0..3: 32-col block within quadrant
    const int fr   = lane & 15;
    const int quad = lane >> 4;
    const int sz   = fr & 7;
    const int ch0  = (quad ^ sz) * 8;        // k-half 0 chunk offset (elems)
    const int ch1  = ((4 + quad) ^ sz) * 8;  // k-half 1

    const int arow = wr * 64 + fr;     // within a 128-row half (+mi*16)
    const int brow = wc * 32 + fr;     // within a 128-row half (+ni*16)

    // Staging: issue i covers tile rows [i*64, i*64+64); half h = issues 2h,2h+1.
    const int srow = t >> 3;                          // 0..63
    const int scol = (((t & 7) ^ (srow & 7)) * 8);
    const bf16_t* gA = A + (size_t)(bm0 + srow) * GK + scol;
    const bf16_t* gB = B + (size_t)(bn0 + srow) * GK + scol;

#define STAGE_A(buf, i, koff) async16(gA + (size_t)((i) * 64) * GK + (koff), \
                                      &As[buf][((i) * 512 + t) * 8])
#define STAGE_B(buf, i, koff) async16(gB + (size_t)((i) * 64) * GK + (koff), \
                                      &Bs[buf][((i) * 512 + t) * 8])

    f32x4 acc[2][2][4][2] = {};   // [mh][nh][mi][ni]

    // ---- prologue: tile0 {A0,B0,B1,A1}, tile1 {A0,B0}; prove tile 0 ----
    STAGE_A(0, 0, 0); STAGE_A(0, 1, 0); STAGE_B(0, 0, 0); STAGE_B(0, 1, 0);
    STAGE_B(0, 2, 0); STAGE_B(0, 3, 0); STAGE_A(0, 2, 0); STAGE_A(0, 3, 0);
    STAGE_A(1, 0, BK); STAGE_A(1, 1, BK); STAGE_B(1, 0, BK); STAGE_B(1, 1, BK);
    asm volatile("s_waitcnt vmcnt(4)" ::: "memory");
    __builtin_amdgcn_s_barrier();
    MEMBAR();

    for (int kt = 0; kt < NT; ++kt) {
        const int cur = kt & 1;
        const bf16_t* Ac = As[cur];
        const bf16_t* Bc = Bs[cur];
        const size_t k1 = (size_t)(kt + 1) * BK;
        const size_t k2 = (size_t)(kt + 2) * BK;

        bf16x8 af[4][2], bf0[2][2], bf1[2][2];

        // ======== P1: quadrant (0,0) ========
#pragma unroll
        for (int ni = 0; ni < 2; ++ni) {
            bf0[ni][0] = *(const bf16x8*)&Bc[(brow + ni * 16) * BK + ch0];
            bf0[ni][1] = *(const bf16x8*)&Bc[(brow + ni * 16) * BK + ch1];
        }
#pragma unroll
        for (int mi = 0; mi < 4; ++mi) {
            af[mi][0] = *(const bf16x8*)&Ac[(arow + mi * 16) * BK + ch0];
            af[mi][1] = *(const bf16x8*)&Ac[(arow + mi * 16) * BK + ch1];
        }
        if (kt + 1 < NT) { STAGE_B(cur ^ 1, 2, k1); STAGE_B(cur ^ 1, 3, k1); }
        MEMBAR();
        __builtin_amdgcn_s_barrier();
        __builtin_amdgcn_sched_barrier(0);
        __builtin_amdgcn_s_setprio(1);
#pragma unroll
        for (int mi = 0; mi < 4; ++mi)
#pragma unroll
            for (int ni = 0; ni < 2; ++ni) {
                acc[0][0][mi][ni] = __builtin_amdgcn_mfma_f32_16x16x32_bf16(
                    af[mi][0], bf0[ni][0], acc[0][0][mi][ni], 0, 0, 0);
                acc[0][0][mi][ni] = __builtin_amdgcn_mfma_f32_16x16x32_bf16(
                    af[mi][1], bf0[ni][1], acc[0][0][mi][ni], 0, 0, 0);
            }
        __builtin_amdgcn_s_setprio(0);
        MEMBAR();
        __builtin_amdgcn_s_barrier();
        MEMBAR();

        // ======== P2: quadrant (0,1) ========
#pragma unroll
        for (int ni = 0; ni < 2; ++ni) {
            bf1[ni][0] = *(const bf16x8*)&Bc[(128 + brow + ni * 16) * BK + ch0];
            bf1[ni][1] = *(const bf16x8*)&Bc[(128 + brow + ni * 16) * BK + ch1];
        }
        if (kt + 1 < NT) { STAGE_A(cur ^ 1, 2, k1); STAGE_A(cur ^ 1, 3, k1); }
        MEMBAR();
        __builtin_amdgcn_s_barrier();
        __builtin_amdgcn_sched_barrier(0);
        __builtin_amdgcn_s_setprio(1);
#pragma unroll
        for (int mi = 0; mi < 4; ++mi)
#pragma unroll
            for (int ni = 0; ni < 2; ++ni) {
                acc[0][1][mi][ni] = __builtin_amdgcn_mfma_f32_16x16x32_bf16(
                    af[mi][0], bf1[ni][0], acc[0][1][mi][ni], 0, 0, 0);
                acc[0][1][mi][ni] = __builtin_amdgcn_mfma_f32_16x16x32_bf16(
                    af[mi][1], bf1[ni][1], acc[0][1][mi][ni], 0, 0, 0);
            }
        __builtin_amdgcn_s_setprio(0);
        MEMBAR();
        __builtin_amdgcn_s_barrier();
        MEMBAR();

        // ======== P3: quadrant (1,0) ========
#pragma unroll
        for (int mi = 0; mi < 4; ++mi) {
            af[mi][0] = *(const bf16x8*)&Ac[(128 + arow + mi * 16) * BK + ch0];
            af[mi][1] = *(const bf16x8*)&Ac[(128 + arow + mi * 16) * BK + ch1];
        }
        if (kt + 2 < NT) { STAGE_A(cur, 0, k2); STAGE_A(cur, 1, k2); }
        MEMBAR();
        __builtin_amdgcn_s_barrier();
        __builtin_amdgcn_sched_barrier(0);
        __builtin_amdgcn_s_setprio(1);
#pragma unroll
        for (int mi = 0; mi < 4; ++mi)
#pragma unroll
            for (int ni = 0; ni < 2; ++ni) {
                acc[1][0][mi][ni] = __builtin_amdgcn_mfma_f32_16x16x32_bf16(
                    af[mi][0], bf0[ni][0], acc[1][0][mi][ni], 0, 0, 0);
                acc[1][0][mi][ni] = __builtin_amdgcn_mfma_f32_16x16x32_bf16(
                    af[mi][1], bf0[ni][1], acc[1][0][mi][ni], 0, 0, 0);
            }
        __builtin_amdgcn_s_setprio(0);
        MEMBAR();
        __builtin_amdgcn_s_barrier();
        MEMBAR();

        // ======== P4: quadrant (1,1) ========
        if (kt + 2 < NT) { STAGE_B(cur, 0, k2); STAGE_B(cur, 1, k2); }
        MEMBAR();
        __builtin_amdgcn_s_barrier();
        __builtin_amdgcn_sched_barrier(0);
        __builtin_amdgcn_s_setprio(1);
#pragma unroll
        for (int mi = 0; mi < 4; ++mi)
#pragma unroll
            for (int ni = 0; ni < 2; ++ni) {
                acc[1][1][mi][ni] = __builtin_amdgcn_mfma_f32_16x16x32_bf16(
                    af[mi][0], bf1[ni][0], acc[1][1][mi][ni], 0, 0, 0);
                acc[1][1][mi][ni] = __builtin_amdgcn_mfma_f32_16x16x32_bf16(
                    af[mi][1], bf1[ni][1], acc[1][1][mi][ni], 0, 0, 0);
            }
        __builtin_amdgcn_s_setprio(0);

        if (kt == NT - 1) break;

        // ---- boundary: counted wait (proves tile kt+1 fully landed) ----
        if (kt < NT - 3) {
            asm volatile("s_waitcnt vmcnt(4)" ::: "memory");
        } else {
            asm volatile("s_waitcnt vmcnt(0)" ::: "memory");
        }
        MEMBAR();
        __builtin_amdgcn_s_barrier();
        MEMBAR();
    }

    // Epilogue: C/D layout col=lane&15, row=quad*4+reg [m89-verified].
    const float scale = 0.022097086912079608f;  // 1/sqrt(2048)
    const int crow0 = bm0 + wr * 64 + (quad << 2);
    const int ccol0 = bn0 + wc * 32 + fr;
#pragma unroll
    for (int mh = 0; mh < 2; ++mh)
#pragma unroll
        for (int nh = 0; nh < 2; ++nh)
#pragma unroll
            for (int ni = 0; ni < 2; ++ni) {
                const int col = ccol0 + nh * 128 + ni * 16;
                const float bv = 0.1f * bias[col];
#pragma unroll
                for (int mi = 0; mi < 4; ++mi) {
                    const int row = crow0 + mh * 128 + mi * 16;
#pragma unroll
                    for (int r = 0; r < 4; ++r)
                        __builtin_nontemporal_store(
                            acc[mh][nh][mi][ni][r] * scale + bv,
                            &C[(size_t)(row + r) * GN + col]);
                }
            }
}

extern "C" void kernel_launch(void* const* d_in, const int* in_sizes, int n_in,
                              void* d_out, int out_size, void* d_ws, size_t ws_size,
                              hipStream_t stream) {
    const float* x = (const float*)d_in[0];   // [16384, 2048]
    const float* w = (const float*)d_in[1];   // [2048, 2048]
    const float* b = (const float*)d_in[2];   // [1, 2048]
    float* out = (float*)d_out;               // [16384, 2048]

    bf16_t* xb = (bf16_t*)d_ws;                   // 64 MiB
    bf16_t* wb = xb + (size_t)NX;                 // + 8 MiB

    cvt_all<<<(NX + NW) / (8 * 256), 256, 0, stream>>>(x, w, xb, wb);

    dim3 grid(GN / BN, GM / BM);   // (8, 64) = 512 blocks
    gemm_bf16_bt<<<grid, 512, 0, stream>>>(xb, wb, b, out);
}